// Round 1
// baseline (240.001 us; speedup 1.0000x reference)
//
#include <hip/hip_runtime.h>
#include <math.h>

#define NB 11
#define PAD 5
#define HEADS 4
#define DIM 128
#define NN 121        // NB*NB
#define S_TOT 484     // HEADS*NN
#define IMG 64
#define LN_EPS 1e-5f

__global__ __launch_bounds__(128) void nca_kernel(
    const float* __restrict__ q, const float* __restrict__ kv,
    const float* __restrict__ pos, const float* __restrict__ w,
    const float* __restrict__ bias, const float* __restrict__ gam,
    const float* __restrict__ bet, float* __restrict__ out)
{
    const int pix = blockIdx.x;          // 0..8191: b*4096 + y*64 + x
    const int x = pix & 63;
    const int y = (pix >> 6) & 63;
    const int b = pix >> 12;
    const int tid = threadIdx.x;

    __shared__ float qs[DIM];
    __shared__ float sc[S_TOT];
    __shared__ float red[4];

    // stage q for this pixel
    qs[tid] = q[(size_t)pix * DIM + tid];
    __syncthreads();

    // ---- scores: s = h*121 + n ----
    // kv slice: cell p = s>>2, channels (s&3)*32 .. +32
    // q  slice: channels (s/121)*32 .. +32
    for (int s = tid; s < S_TOT; s += 128) {
        const int p = s >> 2;
        const int r = s & 3;
        const int i = p / NB, j = p % NB;
        const int yy = y + i - PAD, xx = x + j - PAD;
        const bool inb = ((unsigned)yy < (unsigned)IMG) && ((unsigned)xx < (unsigned)IMG);
        const float* pe = pos + (size_t)p * DIM + r * 32;
        const int qb = (s / NN) * 32;
        float acc = 0.f;
        if (inb) {
            const float* kp = kv + (((size_t)(b * IMG + yy)) * IMG + xx) * DIM + r * 32;
            #pragma unroll
            for (int d = 0; d < 32; ++d)
                acc += (kp[d] + pe[d]) * qs[qb + d];
        } else {
            #pragma unroll
            for (int d = 0; d < 32; ++d)
                acc += pe[d] * qs[qb + d];
        }
        sc[s] = acc;
    }
    __syncthreads();

    // ---- MLP column tid + exact GELU ----
    float acc = bias[tid];
    for (int s = 0; s < S_TOT; ++s)
        acc += sc[s] * w[(size_t)s * DIM + tid];
    const float gel = 0.5f * acc * (1.f + erff(acc * 0.70710678118654752f));
    const float xv = qs[tid] + gel;

    // ---- LayerNorm over 128 channels (2 waves) ----
    const int lane = tid & 63, wv = tid >> 6;
    float sum = xv;
    #pragma unroll
    for (int off = 32; off; off >>= 1) sum += __shfl_down(sum, off, 64);
    if (lane == 0) red[wv] = sum;
    __syncthreads();
    const float mean = (red[0] + red[1]) * (1.f / 128.f);
    const float dv = xv - mean;
    float sq = dv * dv;
    #pragma unroll
    for (int off = 32; off; off >>= 1) sq += __shfl_down(sq, off, 64);
    if (lane == 0) red[wv + 2] = sq;
    __syncthreads();
    const float var = (red[2] + red[3]) * (1.f / 128.f);
    out[(size_t)pix * DIM + tid] = dv * rsqrtf(var + LN_EPS) * gam[tid] + bet[tid];
}

extern "C" void kernel_launch(void* const* d_in, const int* in_sizes, int n_in,
                              void* d_out, int out_size, void* d_ws, size_t ws_size,
                              hipStream_t stream) {
    const float* q    = (const float*)d_in[0];
    const float* kv   = (const float*)d_in[1];
    const float* pos  = (const float*)d_in[2];
    const float* w    = (const float*)d_in[3];
    const float* bias = (const float*)d_in[4];
    const float* gam  = (const float*)d_in[5];
    const float* bet  = (const float*)d_in[6];
    float* out = (float*)d_out;

    const int n_pix = 2 * IMG * IMG;   // 8192
    nca_kernel<<<n_pix, 128, 0, stream>>>(q, kv, pos, w, bias, gam, bet, out);
}

// Round 2
// 203.612 us; speedup vs baseline: 1.1787x; 1.1787x over previous
//
#include <hip/hip_runtime.h>
#include <math.h>

#define NB 11
#define PAD 5
#define DIM 128
#define NN 121        // NB*NB
#define S_TOT 484     // HEADS*NN
#define IMG 64
#define TILE 8        // pixels per block (one row segment)
#define LN_EPS 1e-5f

__global__ __launch_bounds__(256) void nca_kernel(
    const float* __restrict__ q, const float* __restrict__ kv,
    const float* __restrict__ pos, const float* __restrict__ w,
    const float* __restrict__ bias, const float* __restrict__ gam,
    const float* __restrict__ bet, float* __restrict__ out)
{
    const int tile = blockIdx.x;         // 1024 tiles of 8 pixels along x
    const int pix0 = tile * TILE;
    const int x0 = pix0 & 63;
    const int y  = (pix0 >> 6) & 63;
    const int b  = pix0 >> 12;
    const int tid = threadIdx.x;

    __shared__ float qs[TILE][DIM];      // q, later overwritten with x = q+gelu
    __shared__ float sc[TILE][S_TOT];    // scores

    // ---- stage q for 8 pixels (4 KB, coalesced) ----
    for (int i = tid; i < TILE * DIM; i += 256)
        qs[i >> 7][i & 127] = q[(size_t)pix0 * DIM + i];
    __syncthreads();

    // ---- scores: s = h*121 + n; kv slice cell p=s>>2, chans (s&3)*32.. ----
    const float* kvb = kv + (size_t)b * IMG * IMG * DIM;
    for (int it = tid; it < TILE * S_TOT; it += 256) {
        const int pix = it / S_TOT;
        const int s   = it - pix * S_TOT;
        const int p = s >> 2, r = s & 3;
        const int i = p / NB, j = p - i * NB;
        const int yy = y + i - PAD, xx = x0 + pix + j - PAD;
        const int h = s / NN;
        const float4* pe = (const float4*)(pos + (size_t)p * DIM + r * 32);
        const float4* qp = (const float4*)(&qs[pix][h * 32]);
        float acc = 0.f;
        if (((unsigned)yy < (unsigned)IMG) && ((unsigned)xx < (unsigned)IMG)) {
            const float4* kp = (const float4*)(kvb + ((size_t)(yy * IMG + xx)) * DIM + r * 32);
            #pragma unroll
            for (int d = 0; d < 8; ++d) {
                const float4 kq = kp[d], pv = pe[d], qv = qp[d];
                acc += (kq.x + pv.x) * qv.x + (kq.y + pv.y) * qv.y
                     + (kq.z + pv.z) * qv.z + (kq.w + pv.w) * qv.w;
            }
        } else {
            #pragma unroll
            for (int d = 0; d < 8; ++d) {
                const float4 pv = pe[d], qv = qp[d];
                acc += pv.x * qv.x + pv.y * qv.y + pv.z * qv.z + pv.w * qv.w;
            }
        }
        sc[pix][s] = acc;
    }
    __syncthreads();

    // ---- MLP: thread = (channel c, pixel-group pg of 4); 4 acc chains ----
    const int c  = tid & 127;
    const int pg = tid >> 7;             // 0/1 -> pixels pg*4 .. pg*4+3
    const float bv = bias[c];
    float a0 = bv, a1 = bv, a2 = bv, a3 = bv;
    const float* wc = w + c;
    const float* s0 = sc[pg * 4 + 0];
    const float* s1 = sc[pg * 4 + 1];
    const float* s2 = sc[pg * 4 + 2];
    const float* s3 = sc[pg * 4 + 3];
    #pragma unroll 4
    for (int s = 0; s < S_TOT; ++s) {
        const float wv = wc[(size_t)s * DIM];   // coalesced, L1/L2-resident
        a0 += s0[s] * wv;                       // LDS broadcasts
        a1 += s1[s] * wv;
        a2 += s2[s] * wv;
        a3 += s3[s] * wv;
    }
    // exact GELU + residual, write x back into qs
    {
        const float k = 0.70710678118654752f;
        float vals[4] = {a0, a1, a2, a3};
        #pragma unroll
        for (int kk = 0; kk < 4; ++kk) {
            const float v = vals[kk];
            const float g = 0.5f * v * (1.f + erff(v * k));
            qs[pg * 4 + kk][c] += g;            // x = q + gelu(mlp)
        }
    }
    __syncthreads();

    // ---- LayerNorm: each wave owns 2 pixels, butterfly over 64 lanes ----
    const int lane = tid & 63, wid = tid >> 6;
    #pragma unroll
    for (int k = 0; k < 2; ++k) {
        const int pix = wid * 2 + k;
        const float v0 = qs[pix][lane], v1 = qs[pix][lane + 64];
        float sum = v0 + v1;
        #pragma unroll
        for (int off = 1; off < 64; off <<= 1) sum += __shfl_xor(sum, off, 64);
        const float mean = sum * (1.f / 128.f);
        const float d0 = v0 - mean, d1 = v1 - mean;
        float sq = d0 * d0 + d1 * d1;
        #pragma unroll
        for (int off = 1; off < 64; off <<= 1) sq += __shfl_xor(sq, off, 64);
        const float rstd = rsqrtf(sq * (1.f / 128.f) + LN_EPS);
        float* op = out + (size_t)(pix0 + pix) * DIM;
        op[lane]      = d0 * rstd * gam[lane]      + bet[lane];
        op[lane + 64] = d1 * rstd * gam[lane + 64] + bet[lane + 64];
    }
}

extern "C" void kernel_launch(void* const* d_in, const int* in_sizes, int n_in,
                              void* d_out, int out_size, void* d_ws, size_t ws_size,
                              hipStream_t stream) {
    const float* q    = (const float*)d_in[0];
    const float* kv   = (const float*)d_in[1];
    const float* pos  = (const float*)d_in[2];
    const float* w    = (const float*)d_in[3];
    const float* bias = (const float*)d_in[4];
    const float* gam  = (const float*)d_in[5];
    const float* bet  = (const float*)d_in[6];
    float* out = (float*)d_out;

    const int n_blocks = 2 * IMG * IMG / TILE;   // 1024
    nca_kernel<<<n_blocks, 256, 0, stream>>>(q, kv, pos, w, bias, gam, bet, out);
}